// Round 12
// baseline (294.846 us; speedup 1.0000x reference)
//
#include <hip/hip_runtime.h>
#include <hip/hip_bf16.h>

#define S_LEN 2048
#define E_DIM 1024
#define NH 16
#define DH 64

typedef __bf16 v8bf __attribute__((ext_vector_type(8)));
typedef float f32x4 __attribute__((ext_vector_type(4)));
typedef unsigned short u16x4 __attribute__((ext_vector_type(4)));
typedef unsigned short u16x8 __attribute__((ext_vector_type(8)));

// Static device scratch (fully rewritten each launch)
__device__ __align__(16) unsigned short g_Xb[S_LEN * E_DIM];       // x as bf16 [s][e]
__device__ __align__(16) unsigned short g_WT[3 * E_DIM * E_DIM];   // [3072][1024] K-major Wq|Wk|Wv (bf16)
__device__ __align__(16) unsigned short g_WoT[E_DIM * E_DIM];      // [1024][1024] Wo^T (K-major, bf16)
__device__ __align__(16) unsigned short g_Qb[NH * S_LEN * DH];     // [h][s][d]
__device__ __align__(16) unsigned short g_Kb[NH * S_LEN * DH];     // [h][t][d]
__device__ __align__(16) unsigned short g_Vt[NH * DH * S_LEN];     // [h][d][t]  (V transposed)
__device__ __align__(16) unsigned short g_AO[S_LEN * E_DIM];       // [s][h*64+d] (bf16)
__device__ __align__(16) float g_part[1024 * 128 * 64];            // heavy-chunk o partials
__device__ __align__(16) float g_partl[1024 * 128];                // heavy-chunk l partials

__device__ inline unsigned short f2bf(float f) {
    unsigned int u = __float_as_uint(f);
    u += 0x7FFF + ((u >> 16) & 1);   // RNE
    return (unsigned short)(u >> 16);
}
__device__ inline f32x4 mfma16(v8bf a, v8bf b, f32x4 c) {
    return __builtin_amdgcn_mfma_f32_16x16x32_bf16(a, b, c, 0, 0, 0);
}

// async global->LDS, 16B per lane; LDS dest = wave-uniform base + lane*16
typedef __attribute__((address_space(3))) unsigned int lds_u32;
typedef __attribute__((address_space(1))) const unsigned int glb_u32;
__device__ inline void async_cp16(const unsigned short* g, unsigned short* l) {
    __builtin_amdgcn_global_load_lds((glb_u32*)g, (lds_u32*)l, 16, 0, 0);
}

// ---------------- prep: convert x + transpose weights (vectorized) ----------------
__global__ __launch_bounds__(256) void prep(const float* __restrict__ X,
                                            const float* __restrict__ Wq,
                                            const float* __restrict__ Wk,
                                            const float* __restrict__ Wv,
                                            const float* __restrict__ Wo) {
    __shared__ __align__(16) unsigned short lds[64 * 72];
    const int b = blockIdx.x;
    const int t = threadIdx.x;
    if (b < 2048) {
        int i = b * 256 + t;
        f32x4 v = reinterpret_cast<const f32x4*>(X)[i];
        u16x4 o = {f2bf(v.x), f2bf(v.y), f2bf(v.z), f2bf(v.w)};
        reinterpret_cast<u16x4*>(g_Xb)[i] = o;
    } else if (b < 2304) {
        int bb = b - 2048;
        const int h = bb >> 4;
        const int e0 = (bb & 15) * 64;
        const float* srcs[3] = {Wq, Wk, Wv};
#pragma unroll
        for (int tn = 0; tn < 3; tn++) {
            const float* W = srcs[tn] + h * 65536;
#pragma unroll
            for (int p = 0; p < 4; p++) {
                int e = p * 16 + (t >> 4);
                int d = (t & 15) * 4;
                f32x4 v = *reinterpret_cast<const f32x4*>(&W[(e0 + e) * 64 + d]);
                lds[(d + 0) * 72 + e] = f2bf(v.x);
                lds[(d + 1) * 72 + e] = f2bf(v.y);
                lds[(d + 2) * 72 + e] = f2bf(v.z);
                lds[(d + 3) * 72 + e] = f2bf(v.w);
            }
            __syncthreads();
#pragma unroll
            for (int p = 0; p < 2; p++) {
                int d = p * 32 + (t >> 3);
                int ec = (t & 7) * 8;
                u16x8 o = *reinterpret_cast<const u16x8*>(&lds[d * 72 + ec]);
                *reinterpret_cast<u16x8*>(&g_WT[(tn * 1024 + h * 64 + d) * E_DIM + e0 + ec]) = o;
            }
            __syncthreads();
        }
    } else {
        int bb = b - 2304;
        const int f0 = (bb >> 4) * 64;
        const int e0 = (bb & 15) * 64;
#pragma unroll
        for (int p = 0; p < 4; p++) {
            int f = p * 16 + (t >> 4);
            int e = (t & 15) * 4;
            f32x4 v = *reinterpret_cast<const f32x4*>(&Wo[(f0 + f) * E_DIM + e0 + e]);
            lds[(e + 0) * 72 + f] = f2bf(v.x);
            lds[(e + 1) * 72 + f] = f2bf(v.y);
            lds[(e + 2) * 72 + f] = f2bf(v.z);
            lds[(e + 3) * 72 + f] = f2bf(v.w);
        }
        __syncthreads();
#pragma unroll
        for (int p = 0; p < 2; p++) {
            int e = p * 32 + (t >> 3);
            int fc = (t & 7) * 8;
            u16x8 o = *reinterpret_cast<const u16x8*>(&lds[e * 72 + fc]);
            *reinterpret_cast<u16x8*>(&g_WoT[(e0 + e) * E_DIM + f0 + fc]) = o;
        }
    }
}

// ---------------- QKV projection GEMM (128s x 64n, grid (16,48)) ----------------
__global__ __launch_bounds__(256) void qkv_gemm(const float* __restrict__ bq,
                                                const float* __restrict__ bk,
                                                const float* __restrict__ bv) {
    __shared__ __align__(16) unsigned short lds[12288];   // 24KB: lA 128x64, lB 64x64
    unsigned short* lA = lds;
    unsigned short* lB = lds + 8192;
    const int t = threadIdx.x;
    const int wave = t >> 6;
    const int lane = t & 63;
    const int m = lane & 15, quad = lane >> 4;
    const int s0 = blockIdx.x * 128;
    const int n0 = blockIdx.y * 64;

    const int rl = t >> 3;
    const int cx = (t & 7) ^ (rl & 7);
    const int axor = m & 7;

    f32x4 acc[2][4];
#pragma unroll
    for (int i = 0; i < 2; i++)
#pragma unroll
        for (int j = 0; j < 4; j++) acc[i][j] = (f32x4){0.f, 0.f, 0.f, 0.f};

    const unsigned short* lAr0 = lA + (wave * 32 + m) * 64;
    const unsigned short* lAr1 = lA + (wave * 32 + 16 + m) * 64;

    for (int k0 = 0; k0 < E_DIM; k0 += 64) {
        const unsigned short* ga = g_Xb + (s0 + rl) * E_DIM + k0 + cx * 8;
        async_cp16(ga,              lA + wave * 512);
        async_cp16(ga + 32 * E_DIM, lA + 2048 + wave * 512);
        async_cp16(ga + 64 * E_DIM, lA + 4096 + wave * 512);
        async_cp16(ga + 96 * E_DIM, lA + 6144 + wave * 512);
        const unsigned short* gb = g_WT + (n0 + rl) * E_DIM + k0 + cx * 8;
        async_cp16(gb,              lB + wave * 512);
        async_cp16(gb + 32 * E_DIM, lB + 2048 + wave * 512);
        __syncthreads();
#pragma unroll
        for (int ks = 0; ks < 2; ks++) {
            const int ch = ((ks * 4 + quad) ^ axor) * 8;
            v8bf a0 = *reinterpret_cast<const v8bf*>(lAr0 + ch);
            v8bf a1 = *reinterpret_cast<const v8bf*>(lAr1 + ch);
#pragma unroll
            for (int j = 0; j < 4; j++) {
                v8bf bfr = *reinterpret_cast<const v8bf*>(lB + (j * 16 + m) * 64 + ch);
                acc[0][j] = mfma16(a0, bfr, acc[0][j]);
                acc[1][j] = mfma16(a1, bfr, acc[1][j]);
            }
        }
        __syncthreads();
    }

    const int tensor = n0 >> 10;
    const int nn0 = n0 & 1023;
    const int hh = nn0 >> 6;
    const float* bb = tensor == 0 ? bq : (tensor == 1 ? bk : bv);
    float bias[4];
#pragma unroll
    for (int j = 0; j < 4; j++) bias[j] = bb[nn0 + j * 16 + m];

    if (tensor < 2) {
#pragma unroll
        for (int i = 0; i < 2; i++)
#pragma unroll
            for (int j = 0; j < 4; j++)
#pragma unroll
                for (int r = 0; r < 4; r++) {
                    int sl = wave * 32 + i * 16 + quad * 4 + r;
                    int nl = j * 16 + m;
                    lds[sl * 72 + nl] = f2bf(acc[i][j][r] + bias[j]);
                }
        __syncthreads();
        unsigned short* dst = (tensor == 0 ? g_Qb : g_Kb) + (hh * S_LEN + s0) * DH;
#pragma unroll
        for (int p = 0; p < 4; p++) {
            int row = p * 32 + (t >> 3);
            int c = t & 7;
            u16x8 v = *reinterpret_cast<const u16x8*>(&lds[row * 72 + c * 8]);
            *reinterpret_cast<u16x8*>(&dst[row * DH + c * 8]) = v;
        }
    } else {
#pragma unroll
        for (int i = 0; i < 2; i++)
#pragma unroll
            for (int j = 0; j < 4; j++)
#pragma unroll
                for (int r = 0; r < 4; r++) {
                    int sl = wave * 32 + i * 16 + quad * 4 + r;
                    int nl = j * 16 + m;
                    lds[nl * 136 + sl] = f2bf(acc[i][j][r] + bias[j]);
                }
        __syncthreads();
#pragma unroll
        for (int p = 0; p < 4; p++) {
            int nl = p * 16 + (t >> 4);
            int sc = t & 15;
            u16x8 v = *reinterpret_cast<const u16x8*>(&lds[nl * 136 + sc * 8]);
            *reinterpret_cast<u16x8*>(&g_Vt[(hh * DH + nl) * S_LEN + s0 + sc * 8]) = v;
        }
    }
}

// ---------------- causal flash attention (LDS-staged K/V, 128-row q-blocks) ----------------
// Block = 4 waves x 32 q-rows sharing each 64-col K/V tile staged via global_load_lds.
// K-range chunked <=8 iters: per head, tile Tp (128 rows) has nc=ceil((Tp+1)/4) chunks.
// j=0..39 -> (Tp,ci); grid 640 = 16 heads x 40. nc==1: direct bf16 out (waves own rows);
// nc>1: fp32 (o,l) partials (fixed-shift softmax => additive), combined by attn_norm.
__global__ __launch_bounds__(256) void flash_attn() {
    __shared__ __align__(16) unsigned short smem[17408];   // lK 4096 | lV 4096 | P 4x2304
    unsigned short* lK = smem;            // [64 t][64 d], d-chunk xor-swizzled
    unsigned short* lV = smem + 4096;     // [64 d][64 t], t-chunk xor-swizzled
    unsigned short* plds = smem + 8192;
    const int t = threadIdx.x;
    const int wave = t >> 6, lane = t & 63;
    const int m = lane & 15, quad = lane >> 4;
    const int h = blockIdx.x & 15;
    const int j = blockIdx.x >> 4;        // 0..39
    int Tp, ci, nc;
    if (j < 4)        { Tp = j;                ci = 0;            nc = 1; }
    else if (j < 12)  { Tp = 4 + ((j - 4) >> 1);  ci = (j - 4) & 1;  nc = 2; }
    else if (j < 24)  { Tp = 8 + (j - 12) / 3;    ci = (j - 12) % 3; nc = 3; }
    else              { Tp = 12 + ((j - 24) >> 2); ci = (j - 24) & 3; nc = 4; }
    const int s0 = Tp * 128;
    const int U = Tp + 1;                  // 128-col units in causal range
    const int ub = U / nc, ur = U % nc;
    const int units = ub + (ci < ur ? 1 : 0);
    const int su = ci * ub + (ci < ur ? ci : ur);
    const int kBeg = su * 128;
    const int kEnd = kBeg + units * 128;

    const int rowW = s0 + wave * 32;       // this wave's first q-row
    const int rl = t >> 3;                 // staging row 0..31
    const int cx = (t & 7) ^ (rl & 7);     // xor chunk swizzle

    const unsigned short* Qh = g_Qb + h * S_LEN * DH;
    const unsigned short* Kh = g_Kb + h * S_LEN * DH;
    const unsigned short* Vh = g_Vt + h * DH * S_LEN;

    v8bf aqA0 = *reinterpret_cast<const v8bf*>(Qh + (rowW + m) * DH + quad * 8);
    v8bf aqA1 = *reinterpret_cast<const v8bf*>(Qh + (rowW + m) * DH + 32 + quad * 8);
    v8bf aqB0 = *reinterpret_cast<const v8bf*>(Qh + (rowW + 16 + m) * DH + quad * 8);
    v8bf aqB1 = *reinterpret_cast<const v8bf*>(Qh + (rowW + 16 + m) * DH + 32 + quad * 8);

    f32x4 oA[4], oB[4];
#pragma unroll
    for (int i = 0; i < 4; i++) { oA[i] = (f32x4){0.f,0.f,0.f,0.f}; oB[i] = (f32x4){0.f,0.f,0.f,0.f}; }
    f32x4 laccA = (f32x4){0.f,0.f,0.f,0.f}, laccB = (f32x4){0.f,0.f,0.f,0.f};

    v8bf ones;
#pragma unroll
    for (int i = 0; i < 8; i++) ones[i] = (__bf16)1.0f;

    const float SC = 0.125f * 1.44269504088896f;   // 1/sqrt(64) * log2(e)
    unsigned short* pw = plds + wave * 2304;        // this wave's 32x72 P region

    for (int t0 = kBeg; t0 < kEnd; t0 += 64) {
        // stage K tile rows t0..t0+64 (d-major) and V^T rows d=0..64 (t-major)
        const unsigned short* gk = Kh + (t0 + rl) * DH + cx * 8;
        async_cp16(gk,            lK + wave * 512);
        async_cp16(gk + 32 * DH,  lK + 2048 + wave * 512);
        const unsigned short* gv = Vh + rl * S_LEN + t0 + cx * 8;
        async_cp16(gv,                lV + wave * 512);
        async_cp16(gv + 32 * S_LEN,   lV + 2048 + wave * 512);
        __syncthreads();                            // tile ready (drains vmcnt)

        const bool doB = (t0 < rowW + 32);          // wave-uniform
        const bool doA = (t0 < rowW + 16);
        if (doB) {
            v8bf kf[4][2];
#pragma unroll
            for (int ct = 0; ct < 4; ct++) {
                int rr = ct * 16 + m;
#pragma unroll
                for (int half = 0; half < 2; half++)
                    kf[ct][half] = *reinterpret_cast<const v8bf*>(
                        lK + rr * 64 + (((half * 4 + quad) ^ (rr & 7)) * 8));
            }
            f32x4 sB[4];
#pragma unroll
            for (int ct = 0; ct < 4; ct++) {
                sB[ct] = (f32x4){0.f,0.f,0.f,0.f};
                sB[ct] = mfma16(aqB0, kf[ct][0], sB[ct]);
                sB[ct] = mfma16(aqB1, kf[ct][1], sB[ct]);
            }
            f32x4 sA[4];
            if (doA) {
#pragma unroll
                for (int ct = 0; ct < 4; ct++) {
                    sA[ct] = (f32x4){0.f,0.f,0.f,0.f};
                    sA[ct] = mfma16(aqA0, kf[ct][0], sA[ct]);
                    sA[ct] = mfma16(aqA1, kf[ct][1], sA[ct]);
                }
            }
            // causal masks
#pragma unroll
            for (int ct = 0; ct < 4; ct++) {
                int colbase = t0 + ct * 16;
                int col = colbase + m;
                if (colbase + 15 > rowW + 16) {
#pragma unroll
                    for (int r = 0; r < 4; r++)
                        if (col > rowW + 16 + quad * 4 + r) sB[ct][r] = -3e38f;
                }
                if (doA && colbase + 15 > rowW) {
#pragma unroll
                    for (int r = 0; r < 4; r++)
                        if (col > rowW + quad * 4 + r) sA[ct][r] = -3e38f;
                }
            }
            // V frags from LDS (independent of softmax chain)
            v8bf vf[4][2];
#pragma unroll
            for (int dt = 0; dt < 4; dt++) {
                int rv = dt * 16 + m;
#pragma unroll
                for (int half = 0; half < 2; half++)
                    vf[dt][half] = *reinterpret_cast<const v8bf*>(
                        lV + rv * 64 + (((half * 4 + quad) ^ (rv & 7)) * 8));
            }
            // p = exp2(s*SC); packed cvt; P -> per-wave LDS (C->A layout roundtrip)
#pragma unroll
            for (int ct = 0; ct < 4; ct++) {
#pragma unroll
                for (int r = 0; r < 4; r++)
                    sB[ct][r] = __builtin_amdgcn_exp2f(sB[ct][r] * SC);
                __hip_bfloat162 p01 = __float22bfloat162_rn(make_float2(sB[ct][0], sB[ct][1]));
                __hip_bfloat162 p23 = __float22bfloat162_rn(make_float2(sB[ct][2], sB[ct][3]));
                unsigned short* pb = pw + (16 + quad * 4) * 72 + ct * 16 + m;
                pb[0]   = *reinterpret_cast<unsigned short*>(&p01.x);
                pb[72]  = *reinterpret_cast<unsigned short*>(&p01.y);
                pb[144] = *reinterpret_cast<unsigned short*>(&p23.x);
                pb[216] = *reinterpret_cast<unsigned short*>(&p23.y);
            }
            if (doA) {
#pragma unroll
                for (int ct = 0; ct < 4; ct++) {
#pragma unroll
                    for (int r = 0; r < 4; r++)
                        sA[ct][r] = __builtin_amdgcn_exp2f(sA[ct][r] * SC);
                    __hip_bfloat162 p01 = __float22bfloat162_rn(make_float2(sA[ct][0], sA[ct][1]));
                    __hip_bfloat162 p23 = __float22bfloat162_rn(make_float2(sA[ct][2], sA[ct][3]));
                    unsigned short* pa = pw + (quad * 4) * 72 + ct * 16 + m;
                    pa[0]   = *reinterpret_cast<unsigned short*>(&p01.x);
                    pa[72]  = *reinterpret_cast<unsigned short*>(&p01.y);
                    pa[144] = *reinterpret_cast<unsigned short*>(&p23.x);
                    pa[216] = *reinterpret_cast<unsigned short*>(&p23.y);
                }
            }
            __builtin_amdgcn_s_waitcnt(0xC07F);      // lgkmcnt(0): same-wave LDS roundtrip
            v8bf apB0 = *reinterpret_cast<const v8bf*>(pw + (16 + m) * 72 + quad * 8);
            v8bf apB1 = *reinterpret_cast<const v8bf*>(pw + (16 + m) * 72 + 32 + quad * 8);
#pragma unroll
            for (int dt = 0; dt < 4; dt++) {
                oB[dt] = mfma16(apB0, vf[dt][0], oB[dt]);
                oB[dt] = mfma16(apB1, vf[dt][1], oB[dt]);
            }
            laccB = mfma16(apB0, ones, laccB);
            laccB = mfma16(apB1, ones, laccB);
            if (doA) {
                v8bf apA0 = *reinterpret_cast<const v8bf*>(pw + m * 72 + quad * 8);
                v8bf apA1 = *reinterpret_cast<const v8bf*>(pw + m * 72 + 32 + quad * 8);
#pragma unroll
                for (int dt = 0; dt < 4; dt++) {
                    oA[dt] = mfma16(apA0, vf[dt][0], oA[dt]);
                    oA[dt] = mfma16(apA1, vf[dt][1], oA[dt]);
                }
                laccA = mfma16(apA0, ones, laccA);
                laccA = mfma16(apA1, ones, laccA);
            }
        }
        __syncthreads();                            // LDS tile dead before restage
    }

    // epilogue: waves own disjoint rows
    if (nc == 1) {
#pragma unroll
        for (int r = 0; r < 4; r++) {
            float invA = 1.0f / laccA[r];
            float invB = 1.0f / laccB[r];
#pragma unroll
            for (int dt = 0; dt < 4; dt++) {
                g_AO[(rowW + quad * 4 + r) * E_DIM + h * 64 + dt * 16 + m] = f2bf(oA[dt][r] * invA);
                g_AO[(rowW + 16 + quad * 4 + r) * E_DIM + h * 64 + dt * 16 + m] = f2bf(oB[dt][r] * invB);
            }
        }
    } else {
        const int slot = (Tp * 4 + ci) * 16 + h;
        float* po = g_part + (size_t)slot * 8192;
#pragma unroll
        for (int dt = 0; dt < 4; dt++)
#pragma unroll
            for (int r = 0; r < 4; r++) {
                po[(wave * 32 + quad * 4 + r) * 64 + dt * 16 + m]      = oA[dt][r];
                po[(wave * 32 + 16 + quad * 4 + r) * 64 + dt * 16 + m] = oB[dt][r];
            }
        if (m == 0) {
            float* pl = g_partl + slot * 128 + wave * 32;
#pragma unroll
            for (int r = 0; r < 4; r++) {
                pl[quad * 4 + r]      = laccA[r];
                pl[16 + quad * 4 + r] = laccB[r];
            }
        }
    }
}

// ---------------- heavy-chunk combine + normalize (grid 192 = 12 tiles x 16 heads) ----------------
__global__ __launch_bounds__(64) void attn_norm() {
    const int h = blockIdx.x & 15;
    const int Tp = 4 + (blockIdx.x >> 4);          // 4..15
    const int nc = (Tp + 4) >> 2;                  // 2,3,4
    const int s0 = Tp * 128;
    const int d = threadIdx.x;
    const int slot0 = (Tp * 4) * 16 + h;
    for (int row = 0; row < 128; row++) {
        float o = 0.f, l = 0.f;
        for (int cc = 0; cc < nc; cc++) {
            int sl = slot0 + cc * 16;
            o += g_part[(size_t)sl * 8192 + row * 64 + d];
            l += g_partl[sl * 128 + row];
        }
        g_AO[(s0 + row) * E_DIM + h * 64 + d] = f2bf(o / l);
    }
}

// ---------------- output projection (64s x 64n, grid (32,16)) ----------------
__global__ __launch_bounds__(256) void out_gemm(const float* __restrict__ bo,
                                                float* __restrict__ OUT) {
    __shared__ __align__(16) unsigned short lds[8192];
    unsigned short* lA = lds;
    unsigned short* lB = lds + 4096;
    const int t = threadIdx.x;
    const int wave = t >> 6;
    const int lane = t & 63;
    const int m = lane & 15, quad = lane >> 4;
    const int wr = (wave >> 1) * 32, wc = (wave & 1) * 32;
    const int s0 = blockIdx.x * 64;
    const int n0 = blockIdx.y * 64;

    const int rl = t >> 3;
    const int cx = (t & 7) ^ (rl & 7);
    const int axor = m & 7;

    f32x4 acc[2][2];
#pragma unroll
    for (int i = 0; i < 2; i++)
#pragma unroll
        for (int j = 0; j < 2; j++) acc[i][j] = (f32x4){0.f, 0.f, 0.f, 0.f};

    for (int k0 = 0; k0 < E_DIM; k0 += 64) {
        const unsigned short* ga = g_AO + (s0 + rl) * E_DIM + k0 + cx * 8;
        async_cp16(ga,              lA + wave * 512);
        async_cp16(ga + 32 * E_DIM, lA + 2048 + wave * 512);
        const unsigned short* gb = g_WoT + (n0 + rl) * E_DIM + k0 + cx * 8;
        async_cp16(gb,              lB + wave * 512);
        async_cp16(gb + 32 * E_DIM, lB + 2048 + wave * 512);
        __syncthreads();
#pragma unroll
        for (int ks = 0; ks < 2; ks++) {
            const int ch = ((ks * 4 + quad) ^ axor) * 8;
            v8bf a0 = *reinterpret_cast<const v8bf*>(lA + (wr + m) * 64 + ch);
            v8bf a1 = *reinterpret_cast<const v8bf*>(lA + (wr + 16 + m) * 64 + ch);
#pragma unroll
            for (int j = 0; j < 2; j++) {
                v8bf bfr = *reinterpret_cast<const v8bf*>(lB + (wc + j * 16 + m) * 64 + ch);
                acc[0][j] = mfma16(a0, bfr, acc[0][j]);
                acc[1][j] = mfma16(a1, bfr, acc[1][j]);
            }
        }
        __syncthreads();
    }
#pragma unroll
    for (int i = 0; i < 2; i++)
#pragma unroll
        for (int j = 0; j < 2; j++) {
            int e = n0 + wc + j * 16 + m;
            float bias = bo[e];
#pragma unroll
            for (int r = 0; r < 4; r++) {
                int s = s0 + wr + i * 16 + quad * 4 + r;
                OUT[s * E_DIM + e] = acc[i][j][r] + bias;
            }
        }
}

extern "C" void kernel_launch(void* const* d_in, const int* in_sizes, int n_in,
                              void* d_out, int out_size, void* d_ws, size_t ws_size,
                              hipStream_t stream) {
    (void)in_sizes; (void)n_in; (void)out_size; (void)d_ws; (void)ws_size;
    const float* x  = (const float*)d_in[0];
    const float* Wq = (const float*)d_in[1];
    const float* bq = (const float*)d_in[2];
    const float* Wk = (const float*)d_in[3];
    const float* bk = (const float*)d_in[4];
    const float* Wv = (const float*)d_in[5];
    const float* bv = (const float*)d_in[6];
    const float* Wo = (const float*)d_in[7];
    const float* bo = (const float*)d_in[8];
    float* out = (float*)d_out;

    hipLaunchKernelGGL(prep,       dim3(2560),   dim3(256), 0, stream, x, Wq, Wk, Wv, Wo);
    hipLaunchKernelGGL(qkv_gemm,   dim3(16, 48), dim3(256), 0, stream, bq, bk, bv);
    hipLaunchKernelGGL(flash_attn, dim3(640),    dim3(256), 0, stream);
    hipLaunchKernelGGL(attn_norm,  dim3(192),    dim3(64),  0, stream);
    hipLaunchKernelGGL(out_gemm,   dim3(32, 16), dim3(256), 0, stream, bo, out);
}

// Round 13
// 166.995 us; speedup vs baseline: 1.7656x; 1.7656x over previous
//
#include <hip/hip_runtime.h>
#include <hip/hip_bf16.h>

#define S_LEN 2048
#define E_DIM 1024
#define NH 16
#define DH 64

typedef __bf16 v8bf __attribute__((ext_vector_type(8)));
typedef float f32x4 __attribute__((ext_vector_type(4)));
typedef unsigned short u16x4 __attribute__((ext_vector_type(4)));
typedef unsigned short u16x8 __attribute__((ext_vector_type(8)));

// Static device scratch (fully rewritten each launch)
__device__ __align__(16) unsigned short g_Xb[S_LEN * E_DIM];       // x as bf16 [s][e]
__device__ __align__(16) unsigned short g_WT[3 * E_DIM * E_DIM];   // [3072][1024] K-major Wq|Wk|Wv (bf16)
__device__ __align__(16) unsigned short g_WoT[E_DIM * E_DIM];      // [1024][1024] Wo^T (K-major, bf16)
__device__ __align__(16) unsigned short g_Qb[NH * S_LEN * DH];     // [h][s][d]
__device__ __align__(16) unsigned short g_Kb[NH * S_LEN * DH];     // [h][t][d]
__device__ __align__(16) unsigned short g_Vt[NH * DH * S_LEN];     // [h][d][t]  (V transposed)
__device__ __align__(16) unsigned short g_AO[S_LEN * E_DIM];       // [s][h*64+d] (bf16)
__device__ __align__(16) float g_part[1024 * 128 * 64];            // heavy-chunk o partials
__device__ __align__(16) float g_partl[1024 * 128];                // heavy-chunk l partials

__device__ inline unsigned short f2bf(float f) {
    unsigned int u = __float_as_uint(f);
    u += 0x7FFF + ((u >> 16) & 1);   // RNE
    return (unsigned short)(u >> 16);
}
__device__ inline f32x4 mfma16(v8bf a, v8bf b, f32x4 c) {
    return __builtin_amdgcn_mfma_f32_16x16x32_bf16(a, b, c, 0, 0, 0);
}

// async global->LDS, 16B per lane; LDS dest = wave-uniform base + lane*16
typedef __attribute__((address_space(3))) unsigned int lds_u32;
typedef __attribute__((address_space(1))) const unsigned int glb_u32;
__device__ inline void async_cp16(const unsigned short* g, unsigned short* l) {
    __builtin_amdgcn_global_load_lds((glb_u32*)g, (lds_u32*)l, 16, 0, 0);
}

// ---------------- prep: convert x + transpose weights (vectorized) ----------------
__global__ __launch_bounds__(256) void prep(const float* __restrict__ X,
                                            const float* __restrict__ Wq,
                                            const float* __restrict__ Wk,
                                            const float* __restrict__ Wv,
                                            const float* __restrict__ Wo) {
    __shared__ __align__(16) unsigned short lds[64 * 72];
    const int b = blockIdx.x;
    const int t = threadIdx.x;
    if (b < 2048) {
        int i = b * 256 + t;
        f32x4 v = reinterpret_cast<const f32x4*>(X)[i];
        u16x4 o = {f2bf(v.x), f2bf(v.y), f2bf(v.z), f2bf(v.w)};
        reinterpret_cast<u16x4*>(g_Xb)[i] = o;
    } else if (b < 2304) {
        int bb = b - 2048;
        const int h = bb >> 4;
        const int e0 = (bb & 15) * 64;
        const float* srcs[3] = {Wq, Wk, Wv};
#pragma unroll
        for (int tn = 0; tn < 3; tn++) {
            const float* W = srcs[tn] + h * 65536;
#pragma unroll
            for (int p = 0; p < 4; p++) {
                int e = p * 16 + (t >> 4);
                int d = (t & 15) * 4;
                f32x4 v = *reinterpret_cast<const f32x4*>(&W[(e0 + e) * 64 + d]);
                lds[(d + 0) * 72 + e] = f2bf(v.x);
                lds[(d + 1) * 72 + e] = f2bf(v.y);
                lds[(d + 2) * 72 + e] = f2bf(v.z);
                lds[(d + 3) * 72 + e] = f2bf(v.w);
            }
            __syncthreads();
#pragma unroll
            for (int p = 0; p < 2; p++) {
                int d = p * 32 + (t >> 3);
                int ec = (t & 7) * 8;
                u16x8 o = *reinterpret_cast<const u16x8*>(&lds[d * 72 + ec]);
                *reinterpret_cast<u16x8*>(&g_WT[(tn * 1024 + h * 64 + d) * E_DIM + e0 + ec]) = o;
            }
            __syncthreads();
        }
    } else {
        int bb = b - 2304;
        const int f0 = (bb >> 4) * 64;
        const int e0 = (bb & 15) * 64;
#pragma unroll
        for (int p = 0; p < 4; p++) {
            int f = p * 16 + (t >> 4);
            int e = (t & 15) * 4;
            f32x4 v = *reinterpret_cast<const f32x4*>(&Wo[(f0 + f) * E_DIM + e0 + e]);
            lds[(e + 0) * 72 + f] = f2bf(v.x);
            lds[(e + 1) * 72 + f] = f2bf(v.y);
            lds[(e + 2) * 72 + f] = f2bf(v.z);
            lds[(e + 3) * 72 + f] = f2bf(v.w);
        }
        __syncthreads();
#pragma unroll
        for (int p = 0; p < 2; p++) {
            int e = p * 32 + (t >> 3);
            int fc = (t & 7) * 8;
            u16x8 o = *reinterpret_cast<const u16x8*>(&lds[e * 72 + fc]);
            *reinterpret_cast<u16x8*>(&g_WoT[(e0 + e) * E_DIM + f0 + fc]) = o;
        }
    }
}

// ---------------- QKV projection GEMM (128s x 64n, grid (16,48)) ----------------
__global__ __launch_bounds__(256) void qkv_gemm(const float* __restrict__ bq,
                                                const float* __restrict__ bk,
                                                const float* __restrict__ bv) {
    __shared__ __align__(16) unsigned short lds[12288];   // 24KB: lA 128x64, lB 64x64
    unsigned short* lA = lds;
    unsigned short* lB = lds + 8192;
    const int t = threadIdx.x;
    const int wave = t >> 6;
    const int lane = t & 63;
    const int m = lane & 15, quad = lane >> 4;
    const int s0 = blockIdx.x * 128;
    const int n0 = blockIdx.y * 64;

    const int rl = t >> 3;
    const int cx = (t & 7) ^ (rl & 7);
    const int axor = m & 7;

    f32x4 acc[2][4];
#pragma unroll
    for (int i = 0; i < 2; i++)
#pragma unroll
        for (int j = 0; j < 4; j++) acc[i][j] = (f32x4){0.f, 0.f, 0.f, 0.f};

    const unsigned short* lAr0 = lA + (wave * 32 + m) * 64;
    const unsigned short* lAr1 = lA + (wave * 32 + 16 + m) * 64;

    for (int k0 = 0; k0 < E_DIM; k0 += 64) {
        const unsigned short* ga = g_Xb + (s0 + rl) * E_DIM + k0 + cx * 8;
        async_cp16(ga,              lA + wave * 512);
        async_cp16(ga + 32 * E_DIM, lA + 2048 + wave * 512);
        async_cp16(ga + 64 * E_DIM, lA + 4096 + wave * 512);
        async_cp16(ga + 96 * E_DIM, lA + 6144 + wave * 512);
        const unsigned short* gb = g_WT + (n0 + rl) * E_DIM + k0 + cx * 8;
        async_cp16(gb,              lB + wave * 512);
        async_cp16(gb + 32 * E_DIM, lB + 2048 + wave * 512);
        __syncthreads();
#pragma unroll
        for (int ks = 0; ks < 2; ks++) {
            const int ch = ((ks * 4 + quad) ^ axor) * 8;
            v8bf a0 = *reinterpret_cast<const v8bf*>(lAr0 + ch);
            v8bf a1 = *reinterpret_cast<const v8bf*>(lAr1 + ch);
#pragma unroll
            for (int j = 0; j < 4; j++) {
                v8bf bfr = *reinterpret_cast<const v8bf*>(lB + (j * 16 + m) * 64 + ch);
                acc[0][j] = mfma16(a0, bfr, acc[0][j]);
                acc[1][j] = mfma16(a1, bfr, acc[1][j]);
            }
        }
        __syncthreads();
    }

    const int tensor = n0 >> 10;
    const int nn0 = n0 & 1023;
    const int hh = nn0 >> 6;
    const float* bb = tensor == 0 ? bq : (tensor == 1 ? bk : bv);
    float bias[4];
#pragma unroll
    for (int j = 0; j < 4; j++) bias[j] = bb[nn0 + j * 16 + m];

    if (tensor < 2) {
#pragma unroll
        for (int i = 0; i < 2; i++)
#pragma unroll
            for (int j = 0; j < 4; j++)
#pragma unroll
                for (int r = 0; r < 4; r++) {
                    int sl = wave * 32 + i * 16 + quad * 4 + r;
                    int nl = j * 16 + m;
                    lds[sl * 72 + nl] = f2bf(acc[i][j][r] + bias[j]);
                }
        __syncthreads();
        unsigned short* dst = (tensor == 0 ? g_Qb : g_Kb) + (hh * S_LEN + s0) * DH;
#pragma unroll
        for (int p = 0; p < 4; p++) {
            int row = p * 32 + (t >> 3);
            int c = t & 7;
            u16x8 v = *reinterpret_cast<const u16x8*>(&lds[row * 72 + c * 8]);
            *reinterpret_cast<u16x8*>(&dst[row * DH + c * 8]) = v;
        }
    } else {
#pragma unroll
        for (int i = 0; i < 2; i++)
#pragma unroll
            for (int j = 0; j < 4; j++)
#pragma unroll
                for (int r = 0; r < 4; r++) {
                    int sl = wave * 32 + i * 16 + quad * 4 + r;
                    int nl = j * 16 + m;
                    lds[nl * 136 + sl] = f2bf(acc[i][j][r] + bias[j]);
                }
        __syncthreads();
#pragma unroll
        for (int p = 0; p < 4; p++) {
            int nl = p * 16 + (t >> 4);
            int sc = t & 15;
            u16x8 v = *reinterpret_cast<const u16x8*>(&lds[nl * 136 + sc * 8]);
            *reinterpret_cast<u16x8*>(&g_Vt[(hh * DH + nl) * S_LEN + s0 + sc * 8]) = v;
        }
    }
}

// ---------------- causal flash attention (LDS-staged K/V, 128-row q-blocks) ----------------
// Block = 4 waves x 32 q-rows sharing each 64-col K/V tile staged via global_load_lds.
// K-range chunked <=8 iters: per head, tile Tp (128 rows) has nc=ceil((Tp+1)/4) chunks.
// j=0..39 -> (Tp,ci); grid 640 = 16 heads x 40. nc==1: direct bf16 out (waves own rows);
// nc>1: fp32 (o,l) partials (fixed-shift softmax => additive), combined by attn_norm.
__global__ __launch_bounds__(256) void flash_attn() {
    __shared__ __align__(16) unsigned short smem[17408];   // lK 4096 | lV 4096 | P 4x2304
    unsigned short* lK = smem;            // [64 t][64 d], d-chunk xor-swizzled
    unsigned short* lV = smem + 4096;     // [64 d][64 t], t-chunk xor-swizzled
    unsigned short* plds = smem + 8192;
    const int t = threadIdx.x;
    const int wave = t >> 6, lane = t & 63;
    const int m = lane & 15, quad = lane >> 4;
    const int h = blockIdx.x & 15;
    const int j = blockIdx.x >> 4;        // 0..39
    int Tp, ci, nc;
    if (j < 4)        { Tp = j;                ci = 0;            nc = 1; }
    else if (j < 12)  { Tp = 4 + ((j - 4) >> 1);  ci = (j - 4) & 1;  nc = 2; }
    else if (j < 24)  { Tp = 8 + (j - 12) / 3;    ci = (j - 12) % 3; nc = 3; }
    else              { Tp = 12 + ((j - 24) >> 2); ci = (j - 24) & 3; nc = 4; }
    const int s0 = Tp * 128;
    const int U = Tp + 1;                  // 128-col units in causal range
    const int ub = U / nc, ur = U % nc;
    const int units = ub + (ci < ur ? 1 : 0);
    const int su = ci * ub + (ci < ur ? ci : ur);
    const int kBeg = su * 128;
    const int kEnd = kBeg + units * 128;

    const int rowW = s0 + wave * 32;       // this wave's first q-row
    const int rl = t >> 3;                 // staging row 0..31
    const int cx = (t & 7) ^ (rl & 7);     // xor chunk swizzle

    const unsigned short* Qh = g_Qb + h * S_LEN * DH;
    const unsigned short* Kh = g_Kb + h * S_LEN * DH;
    const unsigned short* Vh = g_Vt + h * DH * S_LEN;

    v8bf aqA0 = *reinterpret_cast<const v8bf*>(Qh + (rowW + m) * DH + quad * 8);
    v8bf aqA1 = *reinterpret_cast<const v8bf*>(Qh + (rowW + m) * DH + 32 + quad * 8);
    v8bf aqB0 = *reinterpret_cast<const v8bf*>(Qh + (rowW + 16 + m) * DH + quad * 8);
    v8bf aqB1 = *reinterpret_cast<const v8bf*>(Qh + (rowW + 16 + m) * DH + 32 + quad * 8);

    f32x4 oA[4], oB[4];
#pragma unroll
    for (int i = 0; i < 4; i++) { oA[i] = (f32x4){0.f,0.f,0.f,0.f}; oB[i] = (f32x4){0.f,0.f,0.f,0.f}; }
    f32x4 laccA = (f32x4){0.f,0.f,0.f,0.f}, laccB = (f32x4){0.f,0.f,0.f,0.f};

    v8bf ones;
#pragma unroll
    for (int i = 0; i < 8; i++) ones[i] = (__bf16)1.0f;

    const float SC = 0.125f * 1.44269504088896f;   // 1/sqrt(64) * log2(e)
    unsigned short* pw = plds + wave * 2304;        // this wave's 32x72 P region

    for (int t0 = kBeg; t0 < kEnd; t0 += 64) {
        // stage K tile rows t0..t0+64 (d-major) and V^T rows d=0..64 (t-major)
        const unsigned short* gk = Kh + (t0 + rl) * DH + cx * 8;
        async_cp16(gk,            lK + wave * 512);
        async_cp16(gk + 32 * DH,  lK + 2048 + wave * 512);
        const unsigned short* gv = Vh + rl * S_LEN + t0 + cx * 8;
        async_cp16(gv,                lV + wave * 512);
        async_cp16(gv + 32 * S_LEN,   lV + 2048 + wave * 512);
        __syncthreads();                            // tile ready (drains vmcnt)

        const bool doB = (t0 < rowW + 32);          // wave-uniform
        const bool doA = (t0 < rowW + 16);
        if (doB) {
            v8bf kf[4][2];
#pragma unroll
            for (int ct = 0; ct < 4; ct++) {
                int rr = ct * 16 + m;
#pragma unroll
                for (int half = 0; half < 2; half++)
                    kf[ct][half] = *reinterpret_cast<const v8bf*>(
                        lK + rr * 64 + (((half * 4 + quad) ^ (rr & 7)) * 8));
            }
            f32x4 sB[4];
#pragma unroll
            for (int ct = 0; ct < 4; ct++) {
                sB[ct] = (f32x4){0.f,0.f,0.f,0.f};
                sB[ct] = mfma16(aqB0, kf[ct][0], sB[ct]);
                sB[ct] = mfma16(aqB1, kf[ct][1], sB[ct]);
            }
            f32x4 sA[4];
            if (doA) {
#pragma unroll
                for (int ct = 0; ct < 4; ct++) {
                    sA[ct] = (f32x4){0.f,0.f,0.f,0.f};
                    sA[ct] = mfma16(aqA0, kf[ct][0], sA[ct]);
                    sA[ct] = mfma16(aqA1, kf[ct][1], sA[ct]);
                }
            }
            // causal masks
#pragma unroll
            for (int ct = 0; ct < 4; ct++) {
                int colbase = t0 + ct * 16;
                int col = colbase + m;
                if (colbase + 15 > rowW + 16) {
#pragma unroll
                    for (int r = 0; r < 4; r++)
                        if (col > rowW + 16 + quad * 4 + r) sB[ct][r] = -3e38f;
                }
                if (doA && colbase + 15 > rowW) {
#pragma unroll
                    for (int r = 0; r < 4; r++)
                        if (col > rowW + quad * 4 + r) sA[ct][r] = -3e38f;
                }
            }
            // V frags from LDS (independent of softmax chain)
            v8bf vf[4][2];
#pragma unroll
            for (int dt = 0; dt < 4; dt++) {
                int rv = dt * 16 + m;
#pragma unroll
                for (int half = 0; half < 2; half++)
                    vf[dt][half] = *reinterpret_cast<const v8bf*>(
                        lV + rv * 64 + (((half * 4 + quad) ^ (rv & 7)) * 8));
            }
            // p = exp2(s*SC); packed cvt; P -> per-wave LDS (C->A layout roundtrip)
#pragma unroll
            for (int ct = 0; ct < 4; ct++) {
#pragma unroll
                for (int r = 0; r < 4; r++)
                    sB[ct][r] = __builtin_amdgcn_exp2f(sB[ct][r] * SC);
                __hip_bfloat162 p01 = __float22bfloat162_rn(make_float2(sB[ct][0], sB[ct][1]));
                __hip_bfloat162 p23 = __float22bfloat162_rn(make_float2(sB[ct][2], sB[ct][3]));
                unsigned short* pb = pw + (16 + quad * 4) * 72 + ct * 16 + m;
                pb[0]   = *reinterpret_cast<unsigned short*>(&p01.x);
                pb[72]  = *reinterpret_cast<unsigned short*>(&p01.y);
                pb[144] = *reinterpret_cast<unsigned short*>(&p23.x);
                pb[216] = *reinterpret_cast<unsigned short*>(&p23.y);
            }
            if (doA) {
#pragma unroll
                for (int ct = 0; ct < 4; ct++) {
#pragma unroll
                    for (int r = 0; r < 4; r++)
                        sA[ct][r] = __builtin_amdgcn_exp2f(sA[ct][r] * SC);
                    __hip_bfloat162 p01 = __float22bfloat162_rn(make_float2(sA[ct][0], sA[ct][1]));
                    __hip_bfloat162 p23 = __float22bfloat162_rn(make_float2(sA[ct][2], sA[ct][3]));
                    unsigned short* pa = pw + (quad * 4) * 72 + ct * 16 + m;
                    pa[0]   = *reinterpret_cast<unsigned short*>(&p01.x);
                    pa[72]  = *reinterpret_cast<unsigned short*>(&p01.y);
                    pa[144] = *reinterpret_cast<unsigned short*>(&p23.x);
                    pa[216] = *reinterpret_cast<unsigned short*>(&p23.y);
                }
            }
            __builtin_amdgcn_s_waitcnt(0xC07F);      // lgkmcnt(0): same-wave LDS roundtrip
            v8bf apB0 = *reinterpret_cast<const v8bf*>(pw + (16 + m) * 72 + quad * 8);
            v8bf apB1 = *reinterpret_cast<const v8bf*>(pw + (16 + m) * 72 + 32 + quad * 8);
#pragma unroll
            for (int dt = 0; dt < 4; dt++) {
                oB[dt] = mfma16(apB0, vf[dt][0], oB[dt]);
                oB[dt] = mfma16(apB1, vf[dt][1], oB[dt]);
            }
            laccB = mfma16(apB0, ones, laccB);
            laccB = mfma16(apB1, ones, laccB);
            if (doA) {
                v8bf apA0 = *reinterpret_cast<const v8bf*>(pw + m * 72 + quad * 8);
                v8bf apA1 = *reinterpret_cast<const v8bf*>(pw + m * 72 + 32 + quad * 8);
#pragma unroll
                for (int dt = 0; dt < 4; dt++) {
                    oA[dt] = mfma16(apA0, vf[dt][0], oA[dt]);
                    oA[dt] = mfma16(apA1, vf[dt][1], oA[dt]);
                }
                laccA = mfma16(apA0, ones, laccA);
                laccA = mfma16(apA1, ones, laccA);
            }
        }
        __syncthreads();                            // LDS tile dead before restage
    }

    // epilogue: waves own disjoint rows
    if (nc == 1) {
#pragma unroll
        for (int r = 0; r < 4; r++) {
            float invA = 1.0f / laccA[r];
            float invB = 1.0f / laccB[r];
#pragma unroll
            for (int dt = 0; dt < 4; dt++) {
                g_AO[(rowW + quad * 4 + r) * E_DIM + h * 64 + dt * 16 + m] = f2bf(oA[dt][r] * invA);
                g_AO[(rowW + 16 + quad * 4 + r) * E_DIM + h * 64 + dt * 16 + m] = f2bf(oB[dt][r] * invB);
            }
        }
    } else {
        const int slot = (Tp * 4 + ci) * 16 + h;
        float* po = g_part + (size_t)slot * 8192;
#pragma unroll
        for (int dt = 0; dt < 4; dt++)
#pragma unroll
            for (int r = 0; r < 4; r++) {
                po[(wave * 32 + quad * 4 + r) * 64 + dt * 16 + m]      = oA[dt][r];
                po[(wave * 32 + 16 + quad * 4 + r) * 64 + dt * 16 + m] = oB[dt][r];
            }
        if (m == 0) {
            float* pl = g_partl + slot * 128 + wave * 32;
#pragma unroll
            for (int r = 0; r < 4; r++) {
                pl[quad * 4 + r]      = laccA[r];
                pl[16 + quad * 4 + r] = laccB[r];
            }
        }
    }
}

// ---------------- heavy-chunk combine + normalize (element-parallel) ----------------
// one thread per output element: Tp(12) x row(128) x h(16) x d(64) = 1.57M; grid 6144x256.
// d fastest -> coalesced g_part reads and g_AO writes; g_partl is lane-broadcast.
__global__ __launch_bounds__(256) void attn_norm() {
    int idx = blockIdx.x * 256 + threadIdx.x;
    int d   = idx & 63;
    int h   = (idx >> 6) & 15;
    int row = (idx >> 10) & 127;
    int Tp  = 4 + (idx >> 17);
    int nc  = (Tp + 4) >> 2;                       // 2,3,4
    int slot0 = (Tp * 4) * 16 + h;
    float o = 0.f, l = 0.f;
    for (int cc = 0; cc < nc; cc++) {
        int sl = slot0 + cc * 16;
        o += g_part[(size_t)sl * 8192 + row * 64 + d];
        l += g_partl[sl * 128 + row];
    }
    g_AO[(Tp * 128 + row) * E_DIM + h * 64 + d] = f2bf(o / l);
}

// ---------------- output projection (64s x 64n, grid (32,16)) ----------------
__global__ __launch_bounds__(256) void out_gemm(const float* __restrict__ bo,
                                                float* __restrict__ OUT) {
    __shared__ __align__(16) unsigned short lds[8192];
    unsigned short* lA = lds;
    unsigned short* lB = lds + 4096;
    const int t = threadIdx.x;
    const int wave = t >> 6;
    const int lane = t & 63;
    const int m = lane & 15, quad = lane >> 4;
    const int wr = (wave >> 1) * 32, wc = (wave & 1) * 32;
    const int s0 = blockIdx.x * 64;
    const int n0 = blockIdx.y * 64;

    const int rl = t >> 3;
    const int cx = (t & 7) ^ (rl & 7);
    const int axor = m & 7;

    f32x4 acc[2][2];
#pragma unroll
    for (int i = 0; i < 2; i++)
#pragma unroll
        for (int j = 0; j < 2; j++) acc[i][j] = (f32x4){0.f, 0.f, 0.f, 0.f};

    for (int k0 = 0; k0 < E_DIM; k0 += 64) {
        const unsigned short* ga = g_AO + (s0 + rl) * E_DIM + k0 + cx * 8;
        async_cp16(ga,              lA + wave * 512);
        async_cp16(ga + 32 * E_DIM, lA + 2048 + wave * 512);
        const unsigned short* gb = g_WoT + (n0 + rl) * E_DIM + k0 + cx * 8;
        async_cp16(gb,              lB + wave * 512);
        async_cp16(gb + 32 * E_DIM, lB + 2048 + wave * 512);
        __syncthreads();
#pragma unroll
        for (int ks = 0; ks < 2; ks++) {
            const int ch = ((ks * 4 + quad) ^ axor) * 8;
            v8bf a0 = *reinterpret_cast<const v8bf*>(lA + (wr + m) * 64 + ch);
            v8bf a1 = *reinterpret_cast<const v8bf*>(lA + (wr + 16 + m) * 64 + ch);
#pragma unroll
            for (int j = 0; j < 2; j++) {
                v8bf bfr = *reinterpret_cast<const v8bf*>(lB + (wc + j * 16 + m) * 64 + ch);
                acc[0][j] = mfma16(a0, bfr, acc[0][j]);
                acc[1][j] = mfma16(a1, bfr, acc[1][j]);
            }
        }
        __syncthreads();
    }
#pragma unroll
    for (int i = 0; i < 2; i++)
#pragma unroll
        for (int j = 0; j < 2; j++) {
            int e = n0 + wc + j * 16 + m;
            float bias = bo[e];
#pragma unroll
            for (int r = 0; r < 4; r++) {
                int s = s0 + wr + i * 16 + quad * 4 + r;
                OUT[s * E_DIM + e] = acc[i][j][r] + bias;
            }
        }
}

extern "C" void kernel_launch(void* const* d_in, const int* in_sizes, int n_in,
                              void* d_out, int out_size, void* d_ws, size_t ws_size,
                              hipStream_t stream) {
    (void)in_sizes; (void)n_in; (void)out_size; (void)d_ws; (void)ws_size;
    const float* x  = (const float*)d_in[0];
    const float* Wq = (const float*)d_in[1];
    const float* bq = (const float*)d_in[2];
    const float* Wk = (const float*)d_in[3];
    const float* bk = (const float*)d_in[4];
    const float* Wv = (const float*)d_in[5];
    const float* bv = (const float*)d_in[6];
    const float* Wo = (const float*)d_in[7];
    const float* bo = (const float*)d_in[8];
    float* out = (float*)d_out;

    hipLaunchKernelGGL(prep,       dim3(2560),   dim3(256), 0, stream, x, Wq, Wk, Wv, Wo);
    hipLaunchKernelGGL(qkv_gemm,   dim3(16, 48), dim3(256), 0, stream, bq, bk, bv);
    hipLaunchKernelGGL(flash_attn, dim3(640),    dim3(256), 0, stream);
    hipLaunchKernelGGL(attn_norm,  dim3(6144),   dim3(256), 0, stream);
    hipLaunchKernelGGL(out_gemm,   dim3(32, 16), dim3(256), 0, stream, bo, out);
}